// Round 2
// baseline (149.638 us; speedup 1.0000x reference)
//
#include <hip/hip_runtime.h>

#define HIDN 1024
#define G3 3072
#define NVOCAB 32000

typedef __bf16 bf16x8 __attribute__((ext_vector_type(8)));
typedef float f32x4 __attribute__((ext_vector_type(4)));

__device__ __forceinline__ unsigned short f2bf(float f) {
  union { float f; unsigned int u; } v; v.f = f;
  unsigned int u = v.u;
  return (unsigned short)((u + 0x7fffu + ((u >> 16) & 1u)) >> 16);
}

__device__ __forceinline__ float sigmoidf_(float x) {
  return 1.0f / (1.0f + __expf(-x));
}

// bijective XCD-aware block swizzle (m204 form)
__device__ __forceinline__ int xcd_swz(int orig, int nwg) {
  int q = nwg >> 3, r = nwg & 7;
  int x = orig & 7, i = orig >> 3;
  return (x < r ? x * (q + 1) : r * (q + 1) + (x - r) * q) + i;
}

// ---------------------------------------------------------------------------
// Streaming GEMM: C[128][n0:n0+16] per wave. A: bf16 [128][K] row-major.
// W: fp32 [K][ldw] streamed straight global->reg->bf16 (never staged).
// A staged in LDS per 64-K chunk, double-buffered, XOR-swizzled (p^(row&7))
// so ds_write_b128 / ds_read_b128 are conflict-free. One barrier per chunk;
// next chunk's A-loads are issued right after the barrier and fly under the
// whole compute phase.
// ---------------------------------------------------------------------------
template <int NTHREADS, int NRT>
__device__ __forceinline__ void gemm_stream(
    const unsigned short* __restrict__ A, int K,
    const float* __restrict__ W, int ldw, int n0,
    const float* __restrict__ bias, float* __restrict__ C, int ldc,
    int rt0, unsigned short* lds /* 2 * 8192 ushorts */) {
  constexpr int UPT = 1024 / NTHREADS;  // 16B units per thread per chunk
  const int t = threadIdx.x;
  const int lane = t & 63;
  const int l15 = lane & 15;
  const int kg = lane >> 4;  // 0..3

  f32x4 acc[NRT];
#pragma unroll
  for (int r = 0; r < NRT; ++r) acc[r] = (f32x4)0.0f;

  // per-unit constant addressing (unit = 16B = 8 bf16 of one row)
  size_t goff[UPT];  // A offset in ushorts (add c*64 per chunk)
  int loff[UPT];     // swizzled LDS offset in ushorts
  uint4 rg[UPT];
#pragma unroll
  for (int j = 0; j < UPT; ++j) {
    int u = j * NTHREADS + t;
    int row = u >> 3, p = u & 7;
    goff[j] = (size_t)row * K + p * 8;
    loff[j] = row * 64 + ((p ^ (row & 7)) << 3);
  }

#pragma unroll
  for (int j = 0; j < UPT; ++j)
    rg[j] = *(const uint4*)(A + goff[j]);  // chunk 0

  const int NC = K >> 6;
  for (int c = 0; c < NC; ++c) {
    unsigned short* buf = lds + (c & 1) * 8192;
#pragma unroll
    for (int j = 0; j < UPT; ++j) *(uint4*)(buf + loff[j]) = rg[j];
    __syncthreads();
    if (c + 1 < NC) {
#pragma unroll
      for (int j = 0; j < UPT; ++j)
        rg[j] = *(const uint4*)(A + goff[j] + (c + 1) * 64);
    }

    // hoist all B loads for this chunk (2 x 8 dwords), then convert+MFMA
    float bv[2][8];
#pragma unroll
    for (int kk2 = 0; kk2 < 2; ++kk2) {
      const float* wp =
          W + (size_t)(c * 64 + kk2 * 32 + kg * 8) * ldw + n0 + l15;
#pragma unroll
      for (int j = 0; j < 8; ++j) bv[kk2][j] = wp[(size_t)j * ldw];
    }
#pragma unroll
    for (int kk2 = 0; kk2 < 2; ++kk2) {
      bf16x8 bfr;
#pragma unroll
      for (int j = 0; j < 8; ++j) bfr[j] = (__bf16)bv[kk2][j];
      int k8 = kk2 * 4 + kg;
#pragma unroll
      for (int r = 0; r < NRT; ++r) {
        int row = (rt0 + r) * 16 + l15;
        bf16x8 af = *(const bf16x8*)(buf + row * 64 + ((k8 ^ (row & 7)) << 3));
        acc[r] =
            __builtin_amdgcn_mfma_f32_16x16x32_bf16(af, bfr, acc[r], 0, 0, 0);
      }
    }
  }

  // epilogue: C/D mapping col = lane&15, row = kg*4 + j
#pragma unroll
  for (int r = 0; r < NRT; ++r) {
    int rbase = (rt0 + r) * 16 + kg * 4;
    int col = n0 + l15;
    float bs = bias[col];
#pragma unroll
    for (int j = 0; j < 4; ++j)
      C[(size_t)(rbase + j) * ldc + col] = acc[r][j] + bs;
  }
}

// ---------------------------------------------------------------------------
// prep: h0,h1 -> bf16 ; embedding gather -> bf16
// ---------------------------------------------------------------------------
__global__ __launch_bounds__(256) void prep_kernel(
    const float* __restrict__ h0, const float* __restrict__ h1,
    const float* __restrict__ emb, const int* __restrict__ x,
    unsigned short* __restrict__ h0b, unsigned short* __restrict__ h1b,
    unsigned short* __restrict__ eb) {
  int i = blockIdx.x * 256 + threadIdx.x;
  if (i < 131072) {
    h0b[i] = f2bf(h0[i]);
  } else if (i < 262144) {
    int j = i - 131072;
    h1b[j] = f2bf(h1[j]);
  } else if (i < 294912) {
    int j = i - 262144;
    int b = j >> 8, c = j & 255;
    eb[j] = f2bf(emb[(size_t)x[b] * 256 + c]);
  }
}

// ---------------------------------------------------------------------------
// GRU gemms: 384 blocks (swizzled). Blocks 0..191: gi = X@Wi + bi (col-tile
// bid). Blocks 192..383: gr = H@Wr + br. 4 waves/block: wave w owns rows
// [32w,32w+32) of the block's 16-col stripe.
// ---------------------------------------------------------------------------
__global__ __launch_bounds__(256) void gru_gemms_kernel(
    const unsigned short* __restrict__ Xbf, int KX,
    const float* __restrict__ Wi, const float* __restrict__ bi,
    const unsigned short* __restrict__ Hbf,
    const float* __restrict__ Wr, const float* __restrict__ br,
    float* __restrict__ gi, float* __restrict__ gr) {
  __shared__ unsigned short lds[2 * 8192];
  int bid = xcd_swz(blockIdx.x, 384);
  int w = threadIdx.x >> 6;
  if (bid < 192)
    gemm_stream<256, 2>(Xbf, KX, Wi, G3, bid * 16, bi, gi, G3, 2 * w, lds);
  else
    gemm_stream<256, 2>(Hbf, HIDN, Wr, G3, (bid - 192) * 16, br, gr, G3,
                        2 * w, lds);
}

// ---------------------------------------------------------------------------
// gates: GRU elementwise epilogue; writes h' fp32 (d_out) and bf16 (ws)
// ---------------------------------------------------------------------------
__global__ __launch_bounds__(256) void gates_kernel(
    const float* __restrict__ gi, const float* __restrict__ gr,
    const float* __restrict__ hfp, float* __restrict__ hout,
    unsigned short* __restrict__ hbf) {
  int i = blockIdx.x * 256 + threadIdx.x;  // 131072 total
  int b = i >> 10, n = i & 1023;
  const float* gib = gi + (size_t)b * G3;
  const float* grb = gr + (size_t)b * G3;
  float z = sigmoidf_(gib[n] + grb[n]);
  float r = sigmoidf_(gib[1024 + n] + grb[1024 + n]);
  float hh = tanhf(gib[2048 + n] + r * grb[2048 + n]);
  float h = hfp[i];
  float o = z * h + (1.0f - z) * hh;
  hout[i] = o;
  hbf[i] = f2bf(o);
}

// ---------------------------------------------------------------------------
// FF: logits = h1n @ ffW + ffb   (128x1024 @ 1024x32000)
// 250 blocks x 512 threads; wave w of block b owns col-tile b*8+w.
// ---------------------------------------------------------------------------
__global__ __launch_bounds__(512) void ff_kernel(
    const unsigned short* __restrict__ Abf, const float* __restrict__ W,
    const float* __restrict__ bias, float* __restrict__ C) {
  __shared__ unsigned short lds[2 * 8192];
  int bid = xcd_swz(blockIdx.x, 250);
  int w = threadIdx.x >> 6;
  int ct = bid * 8 + w;
  gemm_stream<512, 8>(Abf, HIDN, W, NVOCAB, ct * 16, bias, C, NVOCAB, 0, lds);
}

extern "C" void kernel_launch(void* const* d_in, const int* in_sizes, int n_in,
                              void* d_out, int out_size, void* d_ws,
                              size_t ws_size, hipStream_t stream) {
  const int* x = (const int*)d_in[0];
  const float* h0 = (const float*)d_in[1];
  const float* h1 = (const float*)d_in[2];
  const float* emb = (const float*)d_in[3];
  const float* Wi0 = (const float*)d_in[4];
  const float* Wr0 = (const float*)d_in[5];
  const float* bi0 = (const float*)d_in[6];
  const float* br0 = (const float*)d_in[7];
  const float* Wi1 = (const float*)d_in[8];
  const float* Wr1 = (const float*)d_in[9];
  const float* bi1 = (const float*)d_in[10];
  const float* br1 = (const float*)d_in[11];
  const float* ffW = (const float*)d_in[12];
  const float* ffb = (const float*)d_in[13];

  float* out = (float*)d_out;
  float* logits = out;          // 128*32000
  float* h0n = out + 4096000;   // 128*1024
  float* h1n = out + 4227072;   // 128*1024

  unsigned short* h0b = (unsigned short*)d_ws;  // 128*1024
  unsigned short* h1b = h0b + 131072;           // 128*1024
  unsigned short* eb = h1b + 131072;            // 128*256
  unsigned short* h0nb = eb + 32768;            // 128*1024
  unsigned short* h1nb = h0nb + 131072;         // 128*1024
  float* gi = (float*)(h1nb + 131072);          // 128*3072
  float* gr = gi + 128 * G3;                    // 128*3072

  prep_kernel<<<1152, 256, 0, stream>>>(h0, h1, emb, x, h0b, h1b, eb);

  // GRU layer 0: x-part uses embedded input (K=256)
  gru_gemms_kernel<<<384, 256, 0, stream>>>(eb, 256, Wi0, bi0, h0b, Wr0, br0,
                                            gi, gr);
  gates_kernel<<<512, 256, 0, stream>>>(gi, gr, h0, h0n, h0nb);

  // GRU layer 1: x-part uses h0n (K=1024)
  gru_gemms_kernel<<<384, 256, 0, stream>>>(h0nb, 1024, Wi1, bi1, h1b, Wr1,
                                            br1, gi, gr);
  gates_kernel<<<512, 256, 0, stream>>>(gi, gr, h1, h1n, h1nb);

  // FF
  ff_kernel<<<250, 512, 0, stream>>>(h1nb, ffW, ffb, logits);
}

// Round 3
// 81.109 us; speedup vs baseline: 1.8449x; 1.8449x over previous
//
#include <hip/hip_runtime.h>

#define HIDN 1024
#define G3 3072
#define NVOCAB 32000

typedef __bf16 bf16x8 __attribute__((ext_vector_type(8)));
typedef float f32x4 __attribute__((ext_vector_type(4)));

__device__ __forceinline__ unsigned short f2bf(float f) {
  union { float f; unsigned int u; } v; v.f = f;
  unsigned int u = v.u;
  return (unsigned short)((u + 0x7fffu + ((u >> 16) & 1u)) >> 16);
}

__device__ __forceinline__ float sigmoidf_(float x) {
  return 1.0f / (1.0f + __expf(-x));
}

// async global->LDS, 16B per lane, LDS dest = uniform base + lane*16
__device__ __forceinline__ void gload16(const void* g, void* l) {
  __builtin_amdgcn_global_load_lds(
      (const __attribute__((address_space(1))) unsigned int*)g,
      (__attribute__((address_space(3))) unsigned int*)l, 16, 0, 0);
}

// ---------------------------------------------------------------------------
// LDS-staged GEMM: C[128][n0:n0+BN] = A(bf16,[128][K]) @ W(f32,[K][ldw]) + b.
// Block = 256 threads (4 waves); wave w computes rows [32w,32w+32) x BN cols.
// BK=32 chunks, double-buffered. Both tiles staged via global_load_lds (16B):
//   B: fp32 row-major [32][BN], linear (fully coalesced 128B-line global
//      reads); frag read = strided ds_read_b32 + cvt to bf16 (MLP-free).
//   A: bf16 [128 rows][32k] = 64B/row; k-units XOR-preswizzled on the GLOBAL
//      source (rule: both-sides-or-neither) so ds_read_b128 is conflict-free.
// One barrier per chunk; chunk c+1's loads are issued before computing c and
// fly under the whole compute phase (queue-depth MLP, no VGPR involvement).
// ---------------------------------------------------------------------------
template <int BN>
__device__ __forceinline__ void gemm_lds(
    const unsigned short* __restrict__ A, int K,
    const float* __restrict__ W, int ldw, int n0,
    const float* __restrict__ bias, float* __restrict__ C, int ldc,
    char* smem) {
  constexpr int NT = BN / 16;
  constexpr int BBYTES = 32 * BN * 4;  // one B buffer
  const int t = threadIdx.x;
  const int w = t >> 6, lane = t & 63;
  const int l15 = lane & 15, kg = lane >> 4;

  f32x4 acc[2][NT];
#pragma unroll
  for (int rt = 0; rt < 2; ++rt)
#pragma unroll
    for (int ct = 0; ct < NT; ++ct) acc[rt][ct] = (f32x4)0.0f;

  // ---- staging (issue only; completion enforced by barrier's vmcnt drain)
  constexpr int BRPI = 256 / BN;  // B rows per 1KB inst
  constexpr int BIW = BN / 32;    // B insts per wave
  const int brw = lane / (BN / 4);      // row within B inst
  const int bcu = lane % (BN / 4);      // 16B unit within B row
  const int arw = lane >> 2;            // row within A inst (16 rows/inst)
  const int ap = lane & 3;              // 16B unit within A row

  auto stage = [&](int c, int sel) {
    char* bbase = smem + sel * BBYTES;
#pragma unroll
    for (int m = 0; m < BIW; ++m) {
      int mi = w * BIW + m;
      int r = mi * BRPI + brw;  // k-row in chunk
      const float* src = W + (size_t)(c * 32 + r) * ldw + n0 + bcu * 4;
      gload16(src, bbase + mi * 1024);
    }
    char* abase = smem + 2 * BBYTES + sel * 8192;
#pragma unroll
    for (int m = 0; m < 2; ++m) {
      int ai = w * 2 + m;
      int row = ai * 16 + arw;
      int psw = ap ^ ((row >> 1) & 3);
      const unsigned short* src = A + (size_t)row * K + c * 32 + psw * 8;
      gload16(src, abase + ai * 1024);
    }
  };

  stage(0, 0);
  __syncthreads();

  const int NC = K >> 5;
  for (int c = 0; c < NC; ++c) {
    int sel = c & 1;
    if (c + 1 < NC) stage(c + 1, sel ^ 1);

    const float* bb = (const float*)(smem + sel * BBYTES);
    const unsigned short* ab =
        (const unsigned short*)(smem + 2 * BBYTES + sel * 8192);

    bf16x8 af[2];
#pragma unroll
    for (int rt = 0; rt < 2; ++rt) {
      int row = (w * 2 + rt) * 16 + l15;
      af[rt] = *(const bf16x8*)(ab + row * 32 + ((kg ^ ((row >> 1) & 3)) << 3));
    }
#pragma unroll
    for (int ct = 0; ct < NT; ++ct) {
      bf16x8 bfr;
#pragma unroll
      for (int j = 0; j < 8; ++j)
        bfr[j] = (__bf16)bb[(kg * 8 + j) * BN + ct * 16 + l15];
#pragma unroll
      for (int rt = 0; rt < 2; ++rt)
        acc[rt][ct] = __builtin_amdgcn_mfma_f32_16x16x32_bf16(
            af[rt], bfr, acc[rt][ct], 0, 0, 0);
    }
    __syncthreads();  // drains this wave's gload_lds queue + syncs buffers
  }

  // epilogue: C/D mapping col = lane&15, row = kg*4 + j
#pragma unroll
  for (int rt = 0; rt < 2; ++rt) {
    int rbase = (w * 2 + rt) * 16 + kg * 4;
#pragma unroll
    for (int ct = 0; ct < NT; ++ct) {
      int col = n0 + ct * 16 + l15;
      float bs = bias[col];
#pragma unroll
      for (int j = 0; j < 4; ++j)
        C[(size_t)(rbase + j) * ldc + col] = acc[rt][ct][j] + bs;
    }
  }
}

// ---------------------------------------------------------------------------
// prep: h0,h1 -> bf16 ; embedding gather -> bf16
// ---------------------------------------------------------------------------
__global__ __launch_bounds__(256) void prep_kernel(
    const float* __restrict__ h0, const float* __restrict__ h1,
    const float* __restrict__ emb, const int* __restrict__ x,
    unsigned short* __restrict__ h0b, unsigned short* __restrict__ h1b,
    unsigned short* __restrict__ eb) {
  int i = blockIdx.x * 256 + threadIdx.x;
  if (i < 131072) {
    h0b[i] = f2bf(h0[i]);
  } else if (i < 262144) {
    int j = i - 131072;
    h1b[j] = f2bf(h1[j]);
  } else if (i < 294912) {
    int j = i - 262144;
    int b = j >> 8, c = j & 255;
    eb[j] = f2bf(emb[(size_t)x[b] * 256 + c]);
  }
}

// ---------------------------------------------------------------------------
// GRU gemms: blocks 0..95 -> gi = X@Wi + bi ; 96..191 -> gr = H@Wr + br
// ---------------------------------------------------------------------------
__global__ __launch_bounds__(256, 2) void gru_gemms_kernel(
    const unsigned short* __restrict__ Xbf, int KX,
    const float* __restrict__ Wi, const float* __restrict__ bi,
    const unsigned short* __restrict__ Hbf,
    const float* __restrict__ Wr, const float* __restrict__ br,
    float* __restrict__ gi, float* __restrict__ gr) {
  __shared__ char smem[2 * 32 * 32 * 4 + 2 * 8192];  // 24 KB
  int blk = blockIdx.x;
  if (blk < 96)
    gemm_lds<32>(Xbf, KX, Wi, G3, blk * 32, bi, gi, G3, smem);
  else
    gemm_lds<32>(Hbf, HIDN, Wr, G3, (blk - 96) * 32, br, gr, G3, smem);
}

// ---------------------------------------------------------------------------
// gates: GRU elementwise epilogue; writes h' fp32 (d_out) and bf16 (ws)
// ---------------------------------------------------------------------------
__global__ __launch_bounds__(256) void gates_kernel(
    const float* __restrict__ gi, const float* __restrict__ gr,
    const float* __restrict__ hfp, float* __restrict__ hout,
    unsigned short* __restrict__ hbf) {
  int i = blockIdx.x * 256 + threadIdx.x;  // 131072 total
  int b = i >> 10, n = i & 1023;
  const float* gib = gi + (size_t)b * G3;
  const float* grb = gr + (size_t)b * G3;
  float z = sigmoidf_(gib[n] + grb[n]);
  float r = sigmoidf_(gib[1024 + n] + grb[1024 + n]);
  float hh = tanhf(gib[2048 + n] + r * grb[2048 + n]);
  float h = hfp[i];
  float o = z * h + (1.0f - z) * hh;
  hout[i] = o;
  hbf[i] = f2bf(o);
}

// ---------------------------------------------------------------------------
// FF: logits = h1n @ ffW + ffb   (128x1024 @ 1024x32000), 250 blocks
// ---------------------------------------------------------------------------
__global__ __launch_bounds__(256, 1) void ff_kernel(
    const unsigned short* __restrict__ Abf, const float* __restrict__ W,
    const float* __restrict__ bias, float* __restrict__ C) {
  __shared__ char smem[2 * 32 * 128 * 4 + 2 * 8192];  // 48 KB
  gemm_lds<128>(Abf, HIDN, W, NVOCAB, blockIdx.x * 128, bias, C, NVOCAB, smem);
}

extern "C" void kernel_launch(void* const* d_in, const int* in_sizes, int n_in,
                              void* d_out, int out_size, void* d_ws,
                              size_t ws_size, hipStream_t stream) {
  const int* x = (const int*)d_in[0];
  const float* h0 = (const float*)d_in[1];
  const float* h1 = (const float*)d_in[2];
  const float* emb = (const float*)d_in[3];
  const float* Wi0 = (const float*)d_in[4];
  const float* Wr0 = (const float*)d_in[5];
  const float* bi0 = (const float*)d_in[6];
  const float* br0 = (const float*)d_in[7];
  const float* Wi1 = (const float*)d_in[8];
  const float* Wr1 = (const float*)d_in[9];
  const float* bi1 = (const float*)d_in[10];
  const float* br1 = (const float*)d_in[11];
  const float* ffW = (const float*)d_in[12];
  const float* ffb = (const float*)d_in[13];

  float* out = (float*)d_out;
  float* logits = out;          // 128*32000
  float* h0n = out + 4096000;   // 128*1024
  float* h1n = out + 4227072;   // 128*1024

  unsigned short* h0b = (unsigned short*)d_ws;  // 128*1024
  unsigned short* h1b = h0b + 131072;           // 128*1024
  unsigned short* eb = h1b + 131072;            // 128*256
  unsigned short* h0nb = eb + 32768;            // 128*1024
  unsigned short* h1nb = h0nb + 131072;         // 128*1024
  float* gi = (float*)(h1nb + 131072);          // 128*3072
  float* gr = gi + 128 * G3;                    // 128*3072

  prep_kernel<<<1152, 256, 0, stream>>>(h0, h1, emb, x, h0b, h1b, eb);

  // GRU layer 0: x-part uses embedded input (K=256)
  gru_gemms_kernel<<<192, 256, 0, stream>>>(eb, 256, Wi0, bi0, h0b, Wr0, br0,
                                            gi, gr);
  gates_kernel<<<512, 256, 0, stream>>>(gi, gr, h0, h0n, h0nb);

  // GRU layer 1: x-part uses h0n (K=1024)
  gru_gemms_kernel<<<192, 256, 0, stream>>>(h0nb, 1024, Wi1, bi1, h1b, Wr1,
                                            br1, gi, gr);
  gates_kernel<<<512, 256, 0, stream>>>(gi, gr, h1, h1n, h1nb);

  // FF
  ff_kernel<<<250, 256, 0, stream>>>(h1nb, ffW, ffb, logits);
}

// Round 4
// 61.812 us; speedup vs baseline: 2.4208x; 1.3122x over previous
//
#include <hip/hip_runtime.h>

#define HIDN 1024
#define G3 3072
#define NVOCAB 32000

typedef __bf16 bf16x8 __attribute__((ext_vector_type(8)));
typedef float f32x4 __attribute__((ext_vector_type(4)));
typedef unsigned short ushort4v __attribute__((ext_vector_type(4)));

__device__ __forceinline__ unsigned short f2bf(float f) {
  union { float f; unsigned int u; } v; v.f = f;
  unsigned int u = v.u;
  return (unsigned short)((u + 0x7fffu + ((u >> 16) & 1u)) >> 16);
}

__device__ __forceinline__ float sigmoidf_(float x) {
  return 1.0f / (1.0f + __expf(-x));
}

// async global->LDS: 16B/lane, LDS dest = wave-uniform base + lane*16
__device__ __forceinline__ void gload16(const void* g, void* l) {
  __builtin_amdgcn_global_load_lds(
      (const __attribute__((address_space(1))) unsigned int*)g,
      (__attribute__((address_space(3))) unsigned int*)l, 16, 0, 0);
}

// ---------------------------------------------------------------------------
// Rows-heavy GEMM core: block = 256 thr (4 waves). Wave w computes ALL 128
// rows x 16 cols (cols w*16..w*16+16 of the block's 64-col stripe at n0).
// K processed in BK=32 chunks over [k0, k0+Kh), double-buffered LDS staged
// entirely via global_load_lds:
//   B tile [32 k][64 col] fp32 (8 KB): row = 16x16B units, unit-XOR-swizzled
//     with sigma(r) = ((r>>3)&1)<<2 (inverse applied on the global source) so
//     the 4 kg-groups of a B-frag read split across bank halves (2-way max).
//     Frag read = 8 x ds_read_b32 + cvt->bf16 (was 64 in the cols-heavy form).
//   A tile [128 row][32 k] bf16 (8 KB): 4x16B units/row, unit-XOR preswizzle
//     (row>>1)&3 so ds_read_b128 frag reads are conflict-free.
// One barrier per chunk; chunk c+1's loads are issued before computing c
// (queue-depth MLP, zero VGPR cost).
// ---------------------------------------------------------------------------
__device__ __forceinline__ void gemm_rows(
    const unsigned short* __restrict__ A, int lda, int k0, int Kh,
    const float* __restrict__ W, int ldw, int n0,
    const float* __restrict__ bias, float* __restrict__ C, int ldc,
    char* smem) {
  const int t = threadIdx.x;
  const int w = t >> 6, lane = t & 63;
  const int l15 = lane & 15, kg = lane >> 4;

  f32x4 acc[8];
#pragma unroll
  for (int r = 0; r < 8; ++r) acc[r] = (f32x4)0.0f;

  // per-lane staging source offsets (2 insts each for A and B per wave)
  size_t srcB[2], srcA[2];
#pragma unroll
  for (int m = 0; m < 2; ++m) {
    int g = (w * 2 + m) * 64 + lane;
    {
      int r = g >> 4, q = g & 15;
      int p = q ^ (((r >> 3) & 1) << 2);
      srcB[m] = (size_t)r * ldw + n0 + p * 4;
    }
    {
      int row = g >> 2, uq = g & 3;
      int up = uq ^ ((row >> 1) & 3);
      srcA[m] = (size_t)row * lda + up * 8;
    }
  }

  auto stage = [&](int c, int sel) {
    char* bb = smem + sel * 8192;
    char* ab = smem + 16384 + sel * 8192;
    int kbase = k0 + c * 32;
#pragma unroll
    for (int m = 0; m < 2; ++m)
      gload16(W + (size_t)kbase * ldw + srcB[m], bb + (w * 2 + m) * 1024);
#pragma unroll
    for (int m = 0; m < 2; ++m)
      gload16(A + srcA[m] + kbase, ab + (w * 2 + m) * 1024);
  };

  stage(0, 0);
  __syncthreads();

  const int NC = Kh >> 5;
  const int cl = w * 16 + l15;  // block-local col
  for (int c = 0; c < NC; ++c) {
    int sel = c & 1;
    if (c + 1 < NC) stage(c + 1, sel ^ 1);

    const float* bbf = (const float*)(smem + sel * 8192);
    const unsigned short* abf =
        (const unsigned short*)(smem + 16384 + sel * 8192);

    bf16x8 bfr;
#pragma unroll
    for (int j = 0; j < 8; ++j) {
      int r = kg * 8 + j;
      int q = (cl >> 2) ^ (((r >> 3) & 1) << 2);
      bfr[j] = (__bf16)bbf[r * 64 + q * 4 + (cl & 3)];
    }
#pragma unroll
    for (int rt = 0; rt < 8; ++rt) {
      int row = rt * 16 + l15;
      bf16x8 af =
          *(const bf16x8*)(abf + row * 32 + ((kg ^ ((row >> 1) & 3)) << 3));
      acc[rt] =
          __builtin_amdgcn_mfma_f32_16x16x32_bf16(af, bfr, acc[rt], 0, 0, 0);
    }
    __syncthreads();  // drains this wave's gload_lds queue; buffers synced
  }

  // epilogue: C/D mapping col = lane&15, row = kg*4 + j
  const int col = n0 + cl;
  const float bs = bias ? bias[col] : 0.0f;
#pragma unroll
  for (int rt = 0; rt < 8; ++rt) {
    int rb = rt * 16 + kg * 4;
#pragma unroll
    for (int j = 0; j < 4; ++j)
      C[(size_t)(rb + j) * ldc + col] = acc[rt][j] + bs;
  }
}

// ---------------------------------------------------------------------------
// prep: h0,h1 -> bf16 ; embedding gather -> bf16 (float4-vectorized)
// ---------------------------------------------------------------------------
__global__ __launch_bounds__(256) void prep_kernel(
    const float* __restrict__ h0, const float* __restrict__ h1,
    const float* __restrict__ emb, const int* __restrict__ x,
    ushort4v* __restrict__ h0b, ushort4v* __restrict__ h1b,
    ushort4v* __restrict__ eb) {
  int i = blockIdx.x * 256 + threadIdx.x;  // 73728 total
  float4 v;
  ushort4v* dst;
  if (i < 32768) {
    v = ((const float4*)h0)[i];
    dst = h0b + i;
  } else if (i < 65536) {
    int j = i - 32768;
    v = ((const float4*)h1)[j];
    dst = h1b + j;
  } else {
    int j = i - 65536;  // 8192
    int b = j >> 6, c = j & 63;
    v = ((const float4*)(emb + (size_t)x[b] * 256))[c];
    dst = eb + j;
  }
  ushort4v o;
  o[0] = f2bf(v.x); o[1] = f2bf(v.y); o[2] = f2bf(v.z); o[3] = f2bf(v.w);
  *dst = o;
}

// ---------------------------------------------------------------------------
// GRU gemms: 192 blocks = {mat: gi|gr} x {ksplit 0|1} x {48 col-blocks}.
// Partial sums (K halves) go to giP/grP[ks]; gates sums them.
// ---------------------------------------------------------------------------
__global__ __launch_bounds__(256) void gru_gemms_kernel(
    const unsigned short* __restrict__ Xbf, int KX,
    const float* __restrict__ Wi, const float* __restrict__ bi,
    const unsigned short* __restrict__ Hbf,
    const float* __restrict__ Wr, const float* __restrict__ br,
    float* __restrict__ giP, float* __restrict__ grP) {
  __shared__ char smem[32768];
  int bid = blockIdx.x;
  int mat = bid / 96, rem = bid % 96;
  int ks = rem / 48, cb = rem % 48;
  if (mat == 0) {
    int Kh = KX >> 1;
    gemm_rows(Xbf, KX, ks * Kh, Kh, Wi, G3, cb * 64, ks ? nullptr : bi,
              giP + (size_t)ks * 128 * G3, G3, smem);
  } else {
    gemm_rows(Hbf, HIDN, ks * 512, 512, Wr, G3, cb * 64, ks ? nullptr : br,
              grP + (size_t)ks * 128 * G3, G3, smem);
  }
}

// ---------------------------------------------------------------------------
// gates: sums K-partials, GRU elementwise; writes h' fp32 + bf16
// ---------------------------------------------------------------------------
__global__ __launch_bounds__(256) void gates_kernel(
    const float* __restrict__ giP, const float* __restrict__ grP,
    const float* __restrict__ hfp, float* __restrict__ hout,
    unsigned short* __restrict__ hbf) {
  int i = blockIdx.x * 256 + threadIdx.x;  // 131072 total
  int b = i >> 10, n = i & 1023;
  const float* g0 = giP + (size_t)b * G3;
  const float* g1 = g0 + (size_t)128 * G3;
  const float* r0 = grP + (size_t)b * G3;
  const float* r1 = r0 + (size_t)128 * G3;
  float iz = g0[n] + g1[n], rz = r0[n] + r1[n];
  float ir = g0[1024 + n] + g1[1024 + n], rr = r0[1024 + n] + r1[1024 + n];
  float ih = g0[2048 + n] + g1[2048 + n], rh = r0[2048 + n] + r1[2048 + n];
  float z = sigmoidf_(iz + rz);
  float r = sigmoidf_(ir + rr);
  float hh = tanhf(ih + r * rh);
  float h = hfp[i];
  float o = z * h + (1.0f - z) * hh;
  hout[i] = o;
  hbf[i] = f2bf(o);
}

// ---------------------------------------------------------------------------
// FF: logits = h1n @ ffW + ffb   (128x1024 @ 1024x32000), 500 blocks x 64 col
// ---------------------------------------------------------------------------
__global__ __launch_bounds__(256) void ff_kernel(
    const unsigned short* __restrict__ Abf, const float* __restrict__ W,
    const float* __restrict__ bias, float* __restrict__ C) {
  __shared__ char smem[32768];
  gemm_rows(Abf, HIDN, 0, HIDN, W, NVOCAB, blockIdx.x * 64, bias, C, NVOCAB,
            smem);
}

extern "C" void kernel_launch(void* const* d_in, const int* in_sizes, int n_in,
                              void* d_out, int out_size, void* d_ws,
                              size_t ws_size, hipStream_t stream) {
  const int* x = (const int*)d_in[0];
  const float* h0 = (const float*)d_in[1];
  const float* h1 = (const float*)d_in[2];
  const float* emb = (const float*)d_in[3];
  const float* Wi0 = (const float*)d_in[4];
  const float* Wr0 = (const float*)d_in[5];
  const float* bi0 = (const float*)d_in[6];
  const float* br0 = (const float*)d_in[7];
  const float* Wi1 = (const float*)d_in[8];
  const float* Wr1 = (const float*)d_in[9];
  const float* bi1 = (const float*)d_in[10];
  const float* br1 = (const float*)d_in[11];
  const float* ffW = (const float*)d_in[12];
  const float* ffb = (const float*)d_in[13];

  float* out = (float*)d_out;
  float* logits = out;          // 128*32000
  float* h0n = out + 4096000;   // 128*1024
  float* h1n = out + 4227072;   // 128*1024

  unsigned short* h0b = (unsigned short*)d_ws;  // 128*1024
  unsigned short* h1b = h0b + 131072;           // 128*1024
  unsigned short* eb = h1b + 131072;            // 128*256
  unsigned short* h0nb = eb + 32768;            // 128*1024
  unsigned short* h1nb = h0nb + 131072;         // 128*1024
  float* giP = (float*)(h1nb + 131072);         // 2 * 128*3072
  float* grP = giP + 2 * 128 * G3;              // 2 * 128*3072

  prep_kernel<<<288, 256, 0, stream>>>(h0, h1, emb, x, (ushort4v*)h0b,
                                       (ushort4v*)h1b, (ushort4v*)eb);

  // GRU layer 0: x-part uses embedded input (K=256)
  gru_gemms_kernel<<<192, 256, 0, stream>>>(eb, 256, Wi0, bi0, h0b, Wr0, br0,
                                            giP, grP);
  gates_kernel<<<512, 256, 0, stream>>>(giP, grP, h0, h0n, h0nb);

  // GRU layer 1: x-part uses h0n (K=1024)
  gru_gemms_kernel<<<192, 256, 0, stream>>>(h0nb, 1024, Wi1, bi1, h1b, Wr1,
                                            br1, giP, grP);
  gates_kernel<<<512, 256, 0, stream>>>(giP, grP, h1, h1n, h1nb);

  // FF
  ff_kernel<<<500, 256, 0, stream>>>(h1nb, ffW, ffb, logits);
}